// Round 21
// baseline (3044.524 us; speedup 1.0000x reference)
//
#include <hip/hip_runtime.h>
#include <hip/hip_bf16.h>
#include <cstdint>
#include <cmath>

constexpr int BATCH = 64;
constexpr int T     = 512;
constexpr int N     = 1024;
constexpr int NWG   = 256;   // persistent workgroups (== CU count)
constexpr int NG    = 32;    // batch groups (2 batches each)
constexpr int GM    = 16;    // member WGs per group

typedef float f4 __attribute__((ext_vector_type(4)));
typedef short bs8 __attribute__((ext_vector_type(8)));  // 8 x bf16 MFMA frag

struct alignas(128) PadInt { int v; int pad[31]; };
__device__ PadInt g_cnt[NG];   // per-group cumulative arrival counters
__device__ PadInt g_flag[NG];  // per-group completed-step counters

// ---- MALL-coherent access helpers (bypass L1+L2) ---------------------------
__device__ __forceinline__ f4 ld_sys_x4(const float* p) {
  f4 v;
  asm volatile("global_load_dwordx4 %0, %1, off sc0 sc1" : "=v"(v) : "v"(p));
  return v;  // NOT ready until wait_vm0()
}
__device__ __forceinline__ int ld_sys_i32(const int* p) {
  int v;
  asm volatile("global_load_dword %0, %1, off sc0 sc1\n\ts_waitcnt vmcnt(0)"
               : "=v"(v) : "v"(p) : "memory");
  return v;
}
__device__ __forceinline__ void st_sys_f32(float* p, float v) {
  asm volatile("global_store_dword %0, %1, off sc0 sc1 nt" ::"v"(p), "v"(v)
               : "memory");
}
__device__ __forceinline__ void wait_vm0(void) {
  asm volatile("s_waitcnt vmcnt(0)" ::: "memory");
  __builtin_amdgcn_sched_barrier(0);
}

__device__ __forceinline__ void arrive_cnt(int g, int t) {
  int old = __hip_atomic_fetch_add(&g_cnt[g].v, 1, __ATOMIC_RELAXED,
                                   __HIP_MEMORY_SCOPE_AGENT);
  if (old == t * GM + (GM - 1))  // last arriver of this step: publish
    __hip_atomic_store(&g_flag[g].v, t + 1, __ATOMIC_RELAXED,
                       __HIP_MEMORY_SCOPE_AGENT);
}
__device__ __forceinline__ void pollf(int g, int e) {
  while (ld_sys_i32(&g_flag[g].v) < e) __builtin_amdgcn_s_sleep(1);
}

// ---- fp32 <-> bf16 (RNE) helpers -------------------------------------------
__device__ __forceinline__ unsigned short f2bf(float f) {
  unsigned u = __builtin_bit_cast(unsigned, f);
  u = u + 0x7FFFu + ((u >> 16) & 1u);
  return (unsigned short)(u >> 16);
}
__device__ __forceinline__ float bf2f(unsigned short b) {
  unsigned u = ((unsigned)b) << 16;
  return __builtin_bit_cast(float, u);
}
// 8 consecutive floats -> hi bf16 frag only (for W-hi)
__device__ __forceinline__ bs8 mk8hi(const float* p) {
  bs8 r;
#pragma unroll
  for (int j = 0; j < 8; ++j) r[j] = (short)f2bf(p[j]);
  return r;
}
// 8 consecutive LDS floats -> hi + lo frags (h in full fp32 precision)
__device__ __forceinline__ void mk8hilo(const float* p, bs8& hi, bs8& lo) {
  f4 a = *reinterpret_cast<const f4*>(p);
  f4 b = *reinterpret_cast<const f4*>(p + 4);
  float v[8] = {a[0], a[1], a[2], a[3], b[0], b[1], b[2], b[3]};
#pragma unroll
  for (int j = 0; j < 8; ++j) {
    unsigned short h = f2bf(v[j]);
    hi[j] = (short)h;
    lo[j] = (short)f2bf(v[j] - bf2f(h));
  }
}

// ---------------------------------------------------------------------------
// W_self = 0.5*(W + W^T); also re-initializes the barrier state.
// ---------------------------------------------------------------------------
__global__ __launch_bounds__(256) void symm_k(const float* __restrict__ W,
                                              float* __restrict__ Ws) {
  if (blockIdx.x == 0 && blockIdx.y == 0 && threadIdx.x < NG) {
    __hip_atomic_store(&g_cnt[threadIdx.x].v, 0, __ATOMIC_RELAXED,
                       __HIP_MEMORY_SCOPE_AGENT);
    __hip_atomic_store(&g_flag[threadIdx.x].v, 0, __ATOMIC_RELAXED,
                       __HIP_MEMORY_SCOPE_AGENT);
  }
  int j = blockIdx.x * 16 + (threadIdx.x & 15);
  int i = blockIdx.y * 16 + (threadIdx.x >> 4);
  Ws[(size_t)i * N + j] = 0.5f * (W[(size_t)i * N + j] + W[(size_t)j * N + i]);
}

// ---------------------------------------------------------------------------
// x_proj = A (M x K) . B^T, B = W_input (N x K) row-major. 128x128 tile.
// XCD-aware swizzle: each XCD owns a contiguous bm chunk x all 8 bn.
// ---------------------------------------------------------------------------
__global__ __launch_bounds__(256) void xproj_gemm(const float* __restrict__ A,
                                                  const float* __restrict__ B,
                                                  float* __restrict__ C,
                                                  int M) {
  constexpr int BM = 128, BN = 128, BK = 16;
  __shared__ float As[BK][BM + 4];
  __shared__ float Bs[BK][BN + 4];

  const int tid = threadIdx.x;
  const int lin = blockIdx.x + gridDim.x * blockIdx.y;  // 0..2047
  const int sw  = ((lin & 7) << 8) + (lin >> 3);        // bijective (2048%8==0)
  const int bm  = sw >> 3;                              // 0..255
  const int bn  = sw & 7;                               // 0..7
  const int tx = tid & 15, ty = tid >> 4;
  const int K = N;

  float acc[8][8];
#pragma unroll
  for (int i = 0; i < 8; ++i)
#pragma unroll
    for (int j = 0; j < 8; ++j) acc[i][j] = 0.f;

  for (int kt = 0; kt < K; kt += BK) {
#pragma unroll
    for (int s = 0; s < 2; ++s) {
      int f = tid + s * 256;
      int row = f >> 2, kq = f & 3;
      float4 a = *reinterpret_cast<const float4*>(
          &A[(size_t)(bm * BM + row) * K + kt + kq * 4]);
      As[kq * 4 + 0][row] = a.x;
      As[kq * 4 + 1][row] = a.y;
      As[kq * 4 + 2][row] = a.z;
      As[kq * 4 + 3][row] = a.w;
      float4 b = *reinterpret_cast<const float4*>(
          &B[(size_t)(bn * BN + row) * K + kt + kq * 4]);
      Bs[kq * 4 + 0][row] = b.x;
      Bs[kq * 4 + 1][row] = b.y;
      Bs[kq * 4 + 2][row] = b.z;
      Bs[kq * 4 + 3][row] = b.w;
    }
    __syncthreads();

#pragma unroll
    for (int k = 0; k < BK; ++k) {
      float a[8], b[8];
      *reinterpret_cast<float4*>(&a[0]) =
          *reinterpret_cast<const float4*>(&As[k][ty * 8]);
      *reinterpret_cast<float4*>(&a[4]) =
          *reinterpret_cast<const float4*>(&As[k][ty * 8 + 4]);
      *reinterpret_cast<float4*>(&b[0]) =
          *reinterpret_cast<const float4*>(&Bs[k][tx * 8]);
      *reinterpret_cast<float4*>(&b[4]) =
          *reinterpret_cast<const float4*>(&Bs[k][tx * 8 + 4]);
#pragma unroll
      for (int i = 0; i < 8; ++i)
#pragma unroll
        for (int j = 0; j < 8; ++j) acc[i][j] = fmaf(a[i], b[j], acc[i][j]);
    }
    __syncthreads();
  }

#pragma unroll
  for (int i = 0; i < 8; ++i) {
    size_t row = (size_t)bm * BM + ty * 8 + i;
#pragma unroll
    for (int j = 0; j < 8; j += 4) {
      *reinterpret_cast<float4*>(&C[row * N + bn * BN + tx * 8 + j]) =
          *reinterpret_cast<const float4*>(&acc[i][j]);
    }
  }
}

// ---------------------------------------------------------------------------
// Persistent recurrence: R17 sync skeleton + 4-pass split-precision MFMA.
// 256 WGs x 640 thr (10 waves), 1 WG/CU (LDS ~154 KiB).  WG (p=wg&15,
// cg=wg>>4): cols m0=cg*64 for groups gA=2p, gB=2p+1 (2 batches each).
// Waves 0-7 compute, K=128 each.  W = Whi + Wlo: Whi bf16 frags in VGPR
// (whi[4 mt][4 kt]); Wlo bf16 in LDS [64][1032] (16B-aligned frags, 2-way
// bank alias = free).  h = hhi + hlo built per step from fp32 LDS.
// acc = Whi*hhi + Whi*hlo + Wlo*hhi + Wlo*hlo  (fp32 MFMA accumulate) ->
// residual step error ~1.6e-5.  K-partials -> red[8][128]; wave 0 sums,
// tanh+xp, stores, acks (1 ack/step/chain).  Sync waves 8/9: unchanged
// R17 handshake + xp prefetch-ahead.  Data path sc0+sc1 / nt (MALL-
// coherent), R7+ lineage.
// ---------------------------------------------------------------------------
__global__ __launch_bounds__(640, 1) void rnn_persist(
    float* __restrict__ out, const float* __restrict__ Ws) {
  const int tid = threadIdx.x;
  const int wg  = blockIdx.x;
  const int p   = wg & 15;
  const int cg  = wg >> 4;
  const int m0  = cg * 64;
  const int gA  = 2 * p, gB = 2 * p + 1;
  const int b0A = gA * 2, b0B = gB * 2;
  const size_t TN = (size_t)T * N;

  __shared__ __align__(16) short wloL[64][1032];   // 132,096 B (W-lo bf16)
  __shared__ __align__(16) float hA[2][1028];      // 8,224 B
  __shared__ __align__(16) float hB[2][1028];      // 8,224 B
  __shared__ float xplA[128], xplB[128];           // 1,024 B
  __shared__ float redA[8 * 128], redB[8 * 128];   // 8,192 B
  __shared__ int lflags[64];
  // [0]=readyA [16]=readyB [8]=wsA [24]=wsB [32]=ackA [48]=ackB

  if (tid == 0) {
    lflags[0] = -1; lflags[16] = -1;
    lflags[8] = 0;  lflags[24] = 0;
    lflags[32] = 0; lflags[48] = 0;
  }

  const int l = tid & 63;
  const int v = tid >> 6;           // 0-7 compute, 8=syncA, 9=syncB

  // ---- prologue: W-lo -> LDS (all threads); W-hi -> VGPR frags ----
  for (int e = tid; e < 64 * 1024; e += 640) {
    int row = e >> 10, k = e & 1023;
    float x = Ws[(size_t)(m0 + row) * N + k];
    unsigned short hi = f2bf(x);
    wloL[row][k] = (short)f2bf(x - bf2f(hi));
  }
  bs8 whi[4][4];  // [mt][kt]: W[m0+16mt+(l&15)][128v+32kt+8*(l>>4) .. +7]
  if (v < 8) {
#pragma unroll
    for (int mt = 0; mt < 4; ++mt)
#pragma unroll
      for (int kt = 0; kt < 4; ++kt)
        whi[mt][kt] = mk8hi(
            &Ws[(size_t)(m0 + 16 * mt + (l & 15)) * N + 128 * v + 32 * kt +
                8 * (l >> 4)]);
  }
  __syncthreads();

  if (v < 8) {
    // ================= COMPUTE WAVES (MFMA) =================
    const int n = l & 15;
    const int koff = 128 * v + 8 * (l >> 4);

    auto do_chain = [&](float (*hX)[1028], float* xplX, float* redX,
                        int rdyIdx, int wsIdx, int ackIdx, int b0, int t) {
      while (*(volatile int*)&lflags[rdyIdx] < t) __builtin_amdgcn_s_sleep(1);
      __builtin_amdgcn_fence(__ATOMIC_ACQUIRE, "workgroup");
      if (t > 0) {
        const float* hrow_ = &hX[n & 1][0];
        f4 acc0 = {0.f, 0.f, 0.f, 0.f}, acc1 = {0.f, 0.f, 0.f, 0.f};
        f4 acc2 = {0.f, 0.f, 0.f, 0.f}, acc3 = {0.f, 0.f, 0.f, 0.f};
#pragma unroll
        for (int kt = 0; kt < 4; ++kt) {
          bs8 bhi, blo;
          mk8hilo(hrow_ + koff + 32 * kt, bhi, blo);
          bs8 wl0 = *reinterpret_cast<const bs8*>(&wloL[n][koff + 32 * kt]);
          bs8 wl1 = *reinterpret_cast<const bs8*>(&wloL[16 + n][koff + 32 * kt]);
          bs8 wl2 = *reinterpret_cast<const bs8*>(&wloL[32 + n][koff + 32 * kt]);
          bs8 wl3 = *reinterpret_cast<const bs8*>(&wloL[48 + n][koff + 32 * kt]);
          acc0 = __builtin_amdgcn_mfma_f32_16x16x32_bf16(whi[0][kt], bhi, acc0, 0, 0, 0);
          acc0 = __builtin_amdgcn_mfma_f32_16x16x32_bf16(whi[0][kt], blo, acc0, 0, 0, 0);
          acc0 = __builtin_amdgcn_mfma_f32_16x16x32_bf16(wl0, bhi, acc0, 0, 0, 0);
          acc0 = __builtin_amdgcn_mfma_f32_16x16x32_bf16(wl0, blo, acc0, 0, 0, 0);
          acc1 = __builtin_amdgcn_mfma_f32_16x16x32_bf16(whi[1][kt], bhi, acc1, 0, 0, 0);
          acc1 = __builtin_amdgcn_mfma_f32_16x16x32_bf16(whi[1][kt], blo, acc1, 0, 0, 0);
          acc1 = __builtin_amdgcn_mfma_f32_16x16x32_bf16(wl1, bhi, acc1, 0, 0, 0);
          acc1 = __builtin_amdgcn_mfma_f32_16x16x32_bf16(wl1, blo, acc1, 0, 0, 0);
          acc2 = __builtin_amdgcn_mfma_f32_16x16x32_bf16(whi[2][kt], bhi, acc2, 0, 0, 0);
          acc2 = __builtin_amdgcn_mfma_f32_16x16x32_bf16(whi[2][kt], blo, acc2, 0, 0, 0);
          acc2 = __builtin_amdgcn_mfma_f32_16x16x32_bf16(wl2, bhi, acc2, 0, 0, 0);
          acc2 = __builtin_amdgcn_mfma_f32_16x16x32_bf16(wl2, blo, acc2, 0, 0, 0);
          acc3 = __builtin_amdgcn_mfma_f32_16x16x32_bf16(whi[3][kt], bhi, acc3, 0, 0, 0);
          acc3 = __builtin_amdgcn_mfma_f32_16x16x32_bf16(whi[3][kt], blo, acc3, 0, 0, 0);
          acc3 = __builtin_amdgcn_mfma_f32_16x16x32_bf16(wl3, bhi, acc3, 0, 0, 0);
          acc3 = __builtin_amdgcn_mfma_f32_16x16x32_bf16(wl3, blo, acc3, 0, 0, 0);
        }
        if (n < 2) {  // D: col=l&15 (batch), row=4*(l>>4)+r (m within tile)
          const int rb = 4 * (l >> 4);
#pragma unroll
          for (int r = 0; r < 4; ++r) {
            redX[v * 128 + (0  + rb + r) * 2 + n] = acc0[r];
            redX[v * 128 + (16 + rb + r) * 2 + n] = acc1[r];
            redX[v * 128 + (32 + rb + r) * 2 + n] = acc2[r];
            redX[v * 128 + (48 + rb + r) * 2 + n] = acc3[r];
          }
        }
      }
      __builtin_amdgcn_fence(__ATOMIC_RELEASE, "workgroup");
      if (l == 0) atomicAdd(&lflags[wsIdx], 1);
      if (v == 0) {
        // wave 0: wait all 8 partials, reduce, activate, store, ack
        while (*(volatile int*)&lflags[wsIdx] < 8 * (t + 1))
          __builtin_amdgcn_s_sleep(1);
        __builtin_amdgcn_fence(__ATOMIC_ACQUIRE, "workgroup");
        float pre0 = 0.f, pre1 = 0.f;
        if (t > 0) {
#pragma unroll
          for (int w = 0; w < 8; ++w) {
            pre0 += redX[w * 128 + l * 2 + 0];
            pre1 += redX[w * 128 + l * 2 + 1];
          }
        }
        float h0 = tanhf(pre0 + xplX[l]);
        float h1 = tanhf(pre1 + xplX[64 + l]);
        st_sys_f32(out + (size_t)(b0 + 0) * TN + (size_t)t * N + m0 + l, h0);
        st_sys_f32(out + (size_t)(b0 + 1) * TN + (size_t)t * N + m0 + l, h1);
        wait_vm0();
        if (l == 0) atomicAdd(&lflags[ackIdx], 1);
      }
    };

    for (int t = 0; t < T; ++t) {
      do_chain(hA, xplA, redA, 0, 8, 32, b0A, t);
      do_chain(hB, xplB, redB, 16, 24, 48, b0B, t);
    }
  } else {
    // ================= SYNC/STAGE WAVES =================
    const bool isB = (v == 9);
    const int lane = l;
    const int g    = isB ? gB : gA;
    const int b0   = isB ? b0B : b0A;
    float (*hb)[1028] = isB ? hB : hA;
    float* xpl = isB ? xplB : xplA;
    volatile int* ready = isB ? (volatile int*)&lflags[16]
                              : (volatile int*)&lflags[0];
    volatile int* cnt = isB ? (volatile int*)&lflags[48]
                            : (volatile int*)&lflags[32];

    const int r = lane >> 5;   // h row 0..1 (32 lanes per row)
    const int c = lane & 31;
    const float* hrow = out + (size_t)(b0 + r) * TN;
    const int xr = lane >> 4, xc = (lane & 15) * 4;  // lane<32: 2 rows x 64 col
    const float* xsrc = out + (size_t)(b0 + xr) * TN + m0 + xc;

    // stage xp(0); publish ready=0; prefetch xp(1) (own cols -> safe early)
    f4 xnext;
    {
      f4 xv;
      if (lane < 32) xv = ld_sys_x4(xsrc);
      wait_vm0();
      if (lane < 32) *reinterpret_cast<f4*>(&xpl[xr * 64 + xc]) = xv;
      __builtin_amdgcn_fence(__ATOMIC_RELEASE, "workgroup");
      if (lane == 0) *ready = 0;
      if (lane < 32) xnext = ld_sys_x4(xsrc + (size_t)N);
    }

    for (int t = 1; t < T; ++t) {
      if (lane == 0) {
        while (*cnt < t) __builtin_amdgcn_s_sleep(1);  // wave0 ack of t-1
        arrive_cnt(g, t - 1);                          // global arrive
        pollf(g, t);                                   // wait group done
      }
      // stage h(t-1) (8 KB); xp(t) already prefetched into registers
      const float* hs = hrow + (size_t)(t - 1) * N;
      f4 tmp[8];
#pragma unroll
      for (int q = 0; q < 8; ++q) tmp[q] = ld_sys_x4(hs + 4 * (c + 32 * q));
      wait_vm0();
#pragma unroll
      for (int q = 0; q < 8; ++q)
        *reinterpret_cast<f4*>(&hb[r][4 * (c + 32 * q)]) = tmp[q];
      if (lane < 32) *reinterpret_cast<f4*>(&xpl[xr * 64 + xc]) = xnext;
      __builtin_amdgcn_fence(__ATOMIC_RELEASE, "workgroup");
      if (lane == 0) *ready = t;
      if (t + 1 < T && lane < 32)
        xnext = ld_sys_x4(xsrc + (size_t)(t + 1) * N);
    }
  }
}

// ---------------------------------------------------------------------------
extern "C" void kernel_launch(void* const* d_in, const int* in_sizes, int n_in,
                              void* d_out, int out_size, void* d_ws,
                              size_t ws_size, hipStream_t stream) {
  const float* in_seq  = (const float*)d_in[0];  // (64,512,1024)
  const float* W_lower = (const float*)d_in[1];  // (1024,1024)
  const float* W_input = (const float*)d_in[2];  // (1024,1024)
  float* out = (float*)d_out;                    // (64,512,1024)
  float* Ws  = (float*)d_ws;                     // 4 MiB scratch

  symm_k<<<dim3(N / 16, N / 16), 256, 0, stream>>>(W_lower, Ws);
  xproj_gemm<<<dim3(N / 128, (BATCH * T) / 128), 256, 0, stream>>>(
      in_seq, W_input, out, BATCH * T);
  rnn_persist<<<NWG, 640, 0, stream>>>(out, Ws);
}

// Round 22
// 2868.929 us; speedup vs baseline: 1.0612x; 1.0612x over previous
//
#include <hip/hip_runtime.h>
#include <cstdint>
#include <cmath>

constexpr int BATCH = 64;
constexpr int T     = 512;
constexpr int N     = 1024;
constexpr int NWG   = 256;   // persistent workgroups (== CU count)
constexpr int NG    = 32;    // batch groups (2 batches each)
constexpr int GM    = 16;    // member WGs per group

typedef float f4 __attribute__((ext_vector_type(4)));
typedef short s4 __attribute__((ext_vector_type(4)));
typedef short bs8 __attribute__((ext_vector_type(8)));  // 8 x bf16 MFMA frag

struct alignas(128) PadInt { int v; int pad[31]; };
__device__ PadInt g_cnt[NG];   // per-group cumulative arrival counters
__device__ PadInt g_flag[NG];  // per-group completed-step counters

// ---- MALL-coherent access helpers (bypass L1+L2) ---------------------------
__device__ __forceinline__ f4 ld_sys_x4(const float* p) {
  f4 v;
  asm volatile("global_load_dwordx4 %0, %1, off sc0 sc1" : "=v"(v) : "v"(p));
  return v;  // NOT ready until wait_vm0()
}
__device__ __forceinline__ int ld_sys_i32(const int* p) {
  int v;
  asm volatile("global_load_dword %0, %1, off sc0 sc1\n\ts_waitcnt vmcnt(0)"
               : "=v"(v) : "v"(p) : "memory");
  return v;
}
__device__ __forceinline__ void st_sys_f32(float* p, float v) {
  asm volatile("global_store_dword %0, %1, off sc0 sc1 nt" ::"v"(p), "v"(v)
               : "memory");
}
__device__ __forceinline__ void wait_vm0(void) {
  asm volatile("s_waitcnt vmcnt(0)" ::: "memory");
  __builtin_amdgcn_sched_barrier(0);
}

__device__ __forceinline__ void arrive_cnt(int g, int t) {
  int old = __hip_atomic_fetch_add(&g_cnt[g].v, 1, __ATOMIC_RELAXED,
                                   __HIP_MEMORY_SCOPE_AGENT);
  if (old == t * GM + (GM - 1))  // last arriver of this step: publish
    __hip_atomic_store(&g_flag[g].v, t + 1, __ATOMIC_RELAXED,
                       __HIP_MEMORY_SCOPE_AGENT);
}
__device__ __forceinline__ void pollf(int g, int e) {
  while (ld_sys_i32(&g_flag[g].v) < e) __builtin_amdgcn_s_sleep(1);
}

// ---- fp32 <-> bf16 (RNE) helpers -------------------------------------------
__device__ __forceinline__ unsigned short f2bf(float f) {
  unsigned u = __builtin_bit_cast(unsigned, f);
  u = u + 0x7FFFu + ((u >> 16) & 1u);
  return (unsigned short)(u >> 16);
}
__device__ __forceinline__ float bf2f(unsigned short b) {
  unsigned u = ((unsigned)b) << 16;
  return __builtin_bit_cast(float, u);
}
// 8 consecutive floats -> hi + lo bf16 frags
__device__ __forceinline__ void mk8hilo(const float* p, bs8& hi, bs8& lo) {
  f4 a = *reinterpret_cast<const f4*>(p);
  f4 b = *reinterpret_cast<const f4*>(p + 4);
  float v[8] = {a[0], a[1], a[2], a[3], b[0], b[1], b[2], b[3]};
#pragma unroll
  for (int j = 0; j < 8; ++j) {
    unsigned short h = f2bf(v[j]);
    hi[j] = (short)h;
    lo[j] = (short)f2bf(v[j] - bf2f(h));
  }
}

// ---------------------------------------------------------------------------
// W_self = 0.5*(W + W^T); also re-initializes the barrier state.
// ---------------------------------------------------------------------------
__global__ __launch_bounds__(256) void symm_k(const float* __restrict__ W,
                                              float* __restrict__ Ws) {
  if (blockIdx.x == 0 && blockIdx.y == 0 && threadIdx.x < NG) {
    __hip_atomic_store(&g_cnt[threadIdx.x].v, 0, __ATOMIC_RELAXED,
                       __HIP_MEMORY_SCOPE_AGENT);
    __hip_atomic_store(&g_flag[threadIdx.x].v, 0, __ATOMIC_RELAXED,
                       __HIP_MEMORY_SCOPE_AGENT);
  }
  int j = blockIdx.x * 16 + (threadIdx.x & 15);
  int i = blockIdx.y * 16 + (threadIdx.x >> 4);
  Ws[(size_t)i * N + j] = 0.5f * (W[(size_t)i * N + j] + W[(size_t)j * N + i]);
}

// ---------------------------------------------------------------------------
// x_proj = A (M x K) . B^T, B = W_input (N x K) row-major. 128x128 tile.
// XCD-aware swizzle: each XCD owns a contiguous bm chunk x all 8 bn.
// ---------------------------------------------------------------------------
__global__ __launch_bounds__(256) void xproj_gemm(const float* __restrict__ A,
                                                  const float* __restrict__ B,
                                                  float* __restrict__ C,
                                                  int M) {
  constexpr int BM = 128, BN = 128, BK = 16;
  __shared__ float As[BK][BM + 4];
  __shared__ float Bs[BK][BN + 4];

  const int tid = threadIdx.x;
  const int lin = blockIdx.x + gridDim.x * blockIdx.y;  // 0..2047
  const int sw  = ((lin & 7) << 8) + (lin >> 3);        // bijective (2048%8==0)
  const int bm  = sw >> 3;                              // 0..255
  const int bn  = sw & 7;                               // 0..7
  const int tx = tid & 15, ty = tid >> 4;
  const int K = N;

  float acc[8][8];
#pragma unroll
  for (int i = 0; i < 8; ++i)
#pragma unroll
    for (int j = 0; j < 8; ++j) acc[i][j] = 0.f;

  for (int kt = 0; kt < K; kt += BK) {
#pragma unroll
    for (int s = 0; s < 2; ++s) {
      int f = tid + s * 256;
      int row = f >> 2, kq = f & 3;
      float4 a = *reinterpret_cast<const float4*>(
          &A[(size_t)(bm * BM + row) * K + kt + kq * 4]);
      As[kq * 4 + 0][row] = a.x;
      As[kq * 4 + 1][row] = a.y;
      As[kq * 4 + 2][row] = a.z;
      As[kq * 4 + 3][row] = a.w;
      float4 b = *reinterpret_cast<const float4*>(
          &B[(size_t)(bn * BN + row) * K + kt + kq * 4]);
      Bs[kq * 4 + 0][row] = b.x;
      Bs[kq * 4 + 1][row] = b.y;
      Bs[kq * 4 + 2][row] = b.z;
      Bs[kq * 4 + 3][row] = b.w;
    }
    __syncthreads();

#pragma unroll
    for (int k = 0; k < BK; ++k) {
      float a[8], b[8];
      *reinterpret_cast<float4*>(&a[0]) =
          *reinterpret_cast<const float4*>(&As[k][ty * 8]);
      *reinterpret_cast<float4*>(&a[4]) =
          *reinterpret_cast<const float4*>(&As[k][ty * 8 + 4]);
      *reinterpret_cast<float4*>(&b[0]) =
          *reinterpret_cast<const float4*>(&Bs[k][tx * 8]);
      *reinterpret_cast<float4*>(&b[4]) =
          *reinterpret_cast<const float4*>(&Bs[k][tx * 8 + 4]);
#pragma unroll
      for (int i = 0; i < 8; ++i)
#pragma unroll
        for (int j = 0; j < 8; ++j) acc[i][j] = fmaf(a[i], b[j], acc[i][j]);
    }
    __syncthreads();
  }

#pragma unroll
  for (int i = 0; i < 8; ++i) {
    size_t row = (size_t)bm * BM + ty * 8 + i;
#pragma unroll
    for (int j = 0; j < 8; j += 4) {
      *reinterpret_cast<float4*>(&C[row * N + bn * BN + tx * 8 + j]) =
          *reinterpret_cast<const float4*>(&acc[i][j]);
    }
  }
}

// ---------------------------------------------------------------------------
// Persistent recurrence: R17 sync skeleton + 3-pass split MFMA, zero
// compute-path converts.  256 WGs x 640 thr, 1 WG/CU (LDS ~157 KiB).
// WG (p=wg&15, cg=wg>>4): cols m0=cg*64, groups gA=2p, gB=2p+1 (2 batches).
// Waves 0-7 compute (K=128 each): Whi bf16 frags in VGPR whi[4][4];
// Wlo bf16 in LDS, FRAGMENT-ORDERED wloF[v][mt][kt][g][n][8] (16B/lane,
// quad=n%8 -> 2-way free).  h staged as pre-split hi/lo bf16 rows
// hs[4][1032] (hi: rows 0-1, lo: rows 2-3) by the SYNC wave -> compute
// reads bs8 directly.  acc = Whi*hhi + Whi*hlo + Wlo*hhi (Wlo*hlo term
// ~5e-5/step, dropped).  K-partials -> red[8][128]; wave 0 reduces,
// tanh+xp, stores, acks.  Sync waves 8/9: R17 handshake + xp prefetch;
// after staging h they convert+split it (one conversion per element).
// Data path sc0+sc1 / nt write-through (MALL-coherent), R7+ lineage.
// ---------------------------------------------------------------------------
__global__ __launch_bounds__(640, 1) void rnn_persist(
    float* __restrict__ out, const float* __restrict__ Ws) {
  const int tid = threadIdx.x;
  const int wg  = blockIdx.x;
  const int p   = wg & 15;
  const int cg  = wg >> 4;
  const int m0  = cg * 64;
  const int gA  = 2 * p, gB = 2 * p + 1;
  const int b0A = gA * 2, b0B = gB * 2;
  const size_t TN = (size_t)T * N;

  __shared__ __align__(16) short wloF[65536];      // 131,072 B (frag-ordered)
  __shared__ __align__(16) short hsA[4][1032];     // 8,256 B (hi,hi,lo,lo)
  __shared__ __align__(16) short hsB[4][1032];     // 8,256 B
  __shared__ float xplA[128], xplB[128];           // 1,024 B
  __shared__ float redA[8 * 128], redB[8 * 128];   // 8,192 B
  __shared__ int lflags[64];
  // [0]=readyA [16]=readyB [8]=wsA [24]=wsB [32]=ackA [48]=ackB

  if (tid == 0) {
    lflags[0] = -1; lflags[16] = -1;
    lflags[8] = 0;  lflags[24] = 0;
    lflags[32] = 0; lflags[48] = 0;
  }

  const int l = tid & 63;
  const int v = tid >> 6;           // 0-7 compute, 8=syncA, 9=syncB
  const int n = l & 15;
  const int g = l >> 4;

  // ---- prologue: Whi -> VGPR frags; Wlo -> fragment-ordered LDS ----
  bs8 whi[4][4];  // [mt][kt]: W[m0+16mt+n][128v+32kt+8g .. +7]
  if (v < 8) {
#pragma unroll
    for (int mt = 0; mt < 4; ++mt)
#pragma unroll
      for (int kt = 0; kt < 4; ++kt) {
        bs8 hi, lo;
        mk8hilo(&Ws[(size_t)(m0 + 16 * mt + n) * N + 128 * v + 32 * kt + 8 * g],
                hi, lo);
        whi[mt][kt] = hi;
        *reinterpret_cast<bs8*>(
            &wloF[((((v * 4 + mt) * 4 + kt) * 4 + g) * 16 + n) * 8]) = lo;
      }
  }
  __syncthreads();

  if (v < 8) {
    // ================= COMPUTE WAVES (MFMA) =================
    const int koff = 128 * v + 8 * g;   // this lane's k base (shorts)
    const int hrow = n & 1;             // batch row for B-fragment

    auto do_chain = [&](short (*hsX)[1032], float* xplX, float* redX,
                        int rdyIdx, int wsIdx, int ackIdx, int b0, int t) {
      while (*(volatile int*)&lflags[rdyIdx] < t) __builtin_amdgcn_s_sleep(1);
      __builtin_amdgcn_fence(__ATOMIC_ACQUIRE, "workgroup");
      if (t > 0) {
        f4 acc0 = {0.f, 0.f, 0.f, 0.f}, acc1 = {0.f, 0.f, 0.f, 0.f};
        f4 acc2 = {0.f, 0.f, 0.f, 0.f}, acc3 = {0.f, 0.f, 0.f, 0.f};
#pragma unroll
        for (int kt = 0; kt < 4; ++kt) {
          bs8 bhi = *reinterpret_cast<const bs8*>(&hsX[hrow][koff + 32 * kt]);
          bs8 blo = *reinterpret_cast<const bs8*>(&hsX[2 + hrow][koff + 32 * kt]);
          bs8 wl0 = *reinterpret_cast<const bs8*>(
              &wloF[((((v * 4 + 0) * 4 + kt) * 4 + g) * 16 + n) * 8]);
          bs8 wl1 = *reinterpret_cast<const bs8*>(
              &wloF[((((v * 4 + 1) * 4 + kt) * 4 + g) * 16 + n) * 8]);
          bs8 wl2 = *reinterpret_cast<const bs8*>(
              &wloF[((((v * 4 + 2) * 4 + kt) * 4 + g) * 16 + n) * 8]);
          bs8 wl3 = *reinterpret_cast<const bs8*>(
              &wloF[((((v * 4 + 3) * 4 + kt) * 4 + g) * 16 + n) * 8]);
          acc0 = __builtin_amdgcn_mfma_f32_16x16x32_bf16(whi[0][kt], bhi, acc0, 0, 0, 0);
          acc0 = __builtin_amdgcn_mfma_f32_16x16x32_bf16(whi[0][kt], blo, acc0, 0, 0, 0);
          acc0 = __builtin_amdgcn_mfma_f32_16x16x32_bf16(wl0, bhi, acc0, 0, 0, 0);
          acc1 = __builtin_amdgcn_mfma_f32_16x16x32_bf16(whi[1][kt], bhi, acc1, 0, 0, 0);
          acc1 = __builtin_amdgcn_mfma_f32_16x16x32_bf16(whi[1][kt], blo, acc1, 0, 0, 0);
          acc1 = __builtin_amdgcn_mfma_f32_16x16x32_bf16(wl1, bhi, acc1, 0, 0, 0);
          acc2 = __builtin_amdgcn_mfma_f32_16x16x32_bf16(whi[2][kt], bhi, acc2, 0, 0, 0);
          acc2 = __builtin_amdgcn_mfma_f32_16x16x32_bf16(whi[2][kt], blo, acc2, 0, 0, 0);
          acc2 = __builtin_amdgcn_mfma_f32_16x16x32_bf16(wl2, bhi, acc2, 0, 0, 0);
          acc3 = __builtin_amdgcn_mfma_f32_16x16x32_bf16(whi[3][kt], bhi, acc3, 0, 0, 0);
          acc3 = __builtin_amdgcn_mfma_f32_16x16x32_bf16(whi[3][kt], blo, acc3, 0, 0, 0);
          acc3 = __builtin_amdgcn_mfma_f32_16x16x32_bf16(wl3, bhi, acc3, 0, 0, 0);
        }
        if (n < 2) {  // D: col=n (batch), row=4g+r (m within 16-tile)
          const int rb = 4 * g;
#pragma unroll
          for (int r = 0; r < 4; ++r) {
            redX[v * 128 + (0  + rb + r) * 2 + n] = acc0[r];
            redX[v * 128 + (16 + rb + r) * 2 + n] = acc1[r];
            redX[v * 128 + (32 + rb + r) * 2 + n] = acc2[r];
            redX[v * 128 + (48 + rb + r) * 2 + n] = acc3[r];
          }
        }
      }
      __builtin_amdgcn_fence(__ATOMIC_RELEASE, "workgroup");
      if (l == 0) atomicAdd(&lflags[wsIdx], 1);
      if (v == 0) {
        // wave 0: wait all 8 partials, reduce, activate, store, ack
        while (*(volatile int*)&lflags[wsIdx] < 8 * (t + 1))
          __builtin_amdgcn_s_sleep(1);
        __builtin_amdgcn_fence(__ATOMIC_ACQUIRE, "workgroup");
        float pre0 = 0.f, pre1 = 0.f;
        if (t > 0) {
#pragma unroll
          for (int w = 0; w < 8; ++w) {
            pre0 += redX[w * 128 + l * 2 + 0];
            pre1 += redX[w * 128 + l * 2 + 1];
          }
        }
        float h0 = tanhf(pre0 + xplX[l]);
        float h1 = tanhf(pre1 + xplX[64 + l]);
        st_sys_f32(out + (size_t)(b0 + 0) * TN + (size_t)t * N + m0 + l, h0);
        st_sys_f32(out + (size_t)(b0 + 1) * TN + (size_t)t * N + m0 + l, h1);
        wait_vm0();
        if (l == 0) atomicAdd(&lflags[ackIdx], 1);
      }
    };

    for (int t = 0; t < T; ++t) {
      do_chain(hsA, xplA, redA, 0, 8, 32, b0A, t);
      do_chain(hsB, xplB, redB, 16, 24, 48, b0B, t);
    }
  } else {
    // ================= SYNC/STAGE WAVES =================
    const bool isB = (v == 9);
    const int lane = l;
    const int grp  = isB ? gB : gA;
    const int b0   = isB ? b0B : b0A;
    short (*hsb)[1032] = isB ? hsB : hsA;
    float* xpl = isB ? xplB : xplA;
    volatile int* ready = isB ? (volatile int*)&lflags[16]
                              : (volatile int*)&lflags[0];
    volatile int* cnt = isB ? (volatile int*)&lflags[48]
                            : (volatile int*)&lflags[32];

    const int r = lane >> 5;   // h row 0..1 (32 lanes per row)
    const int c = lane & 31;
    const float* hrow = out + (size_t)(b0 + r) * TN;
    const int xr = lane >> 4, xc = (lane & 15) * 4;  // lane<32: 2 rows x 64 col
    const float* xsrc = out + (size_t)(b0 + xr) * TN + m0 + xc;

    // stage xp(0); publish ready=0; prefetch xp(1) (own cols -> safe early)
    f4 xnext;
    {
      f4 xv;
      if (lane < 32) xv = ld_sys_x4(xsrc);
      wait_vm0();
      if (lane < 32) *reinterpret_cast<f4*>(&xpl[xr * 64 + xc]) = xv;
      __builtin_amdgcn_fence(__ATOMIC_RELEASE, "workgroup");
      if (lane == 0) *ready = 0;
      if (lane < 32) xnext = ld_sys_x4(xsrc + (size_t)N);
    }

    for (int t = 1; t < T; ++t) {
      if (lane == 0) {
        while (*cnt < t) __builtin_amdgcn_s_sleep(1);  // wave0 ack of t-1
        arrive_cnt(grp, t - 1);                        // global arrive
        pollf(grp, t);                                 // wait group done
      }
      // stage h(t-1) (8 KB) and SPLIT to hi/lo bf16 rows
      const float* hs = hrow + (size_t)(t - 1) * N;
      f4 tmp[8];
#pragma unroll
      for (int q = 0; q < 8; ++q) tmp[q] = ld_sys_x4(hs + 4 * (c + 32 * q));
      wait_vm0();
#pragma unroll
      for (int q = 0; q < 8; ++q) {
        s4 hi4, lo4;
#pragma unroll
        for (int j = 0; j < 4; ++j) {
          float x = tmp[q][j];
          unsigned short h = f2bf(x);
          hi4[j] = (short)h;
          lo4[j] = (short)f2bf(x - bf2f(h));
        }
        *reinterpret_cast<s4*>(&hsb[r][4 * (c + 32 * q)]) = hi4;
        *reinterpret_cast<s4*>(&hsb[2 + r][4 * (c + 32 * q)]) = lo4;
      }
      if (lane < 32) *reinterpret_cast<f4*>(&xpl[xr * 64 + xc]) = xnext;
      __builtin_amdgcn_fence(__ATOMIC_RELEASE, "workgroup");
      if (lane == 0) *ready = t;
      if (t + 1 < T && lane < 32)
        xnext = ld_sys_x4(xsrc + (size_t)(t + 1) * N);
    }
  }
}

// ---------------------------------------------------------------------------
extern "C" void kernel_launch(void* const* d_in, const int* in_sizes, int n_in,
                              void* d_out, int out_size, void* d_ws,
                              size_t ws_size, hipStream_t stream) {
  const float* in_seq  = (const float*)d_in[0];  // (64,512,1024)
  const float* W_lower = (const float*)d_in[1];  // (1024,1024)
  const float* W_input = (const float*)d_in[2];  // (1024,1024)
  float* out = (float*)d_out;                    // (64,512,1024)
  float* Ws  = (float*)d_ws;                     // 4 MiB scratch

  symm_k<<<dim3(N / 16, N / 16), 256, 0, stream>>>(W_lower, Ws);
  xproj_gemm<<<dim3(N / 128, (BATCH * T) / 128), 256, 0, stream>>>(
      in_seq, W_input, out, BATCH * T);
  rnn_persist<<<NWG, 640, 0, stream>>>(out, Ws);
}

// Round 23
// 2779.222 us; speedup vs baseline: 1.0955x; 1.0323x over previous
//
#include <hip/hip_runtime.h>
#include <cstdint>
#include <cmath>

constexpr int BATCH = 64;
constexpr int T     = 512;
constexpr int N     = 1024;
constexpr int NWG   = 256;   // persistent workgroups (== CU count)
constexpr int NG    = 32;    // batch groups (2 batches each)
constexpr int GM    = 16;    // member WGs per group

typedef float f4 __attribute__((ext_vector_type(4)));
typedef short s4 __attribute__((ext_vector_type(4)));
typedef short bs8 __attribute__((ext_vector_type(8)));  // 8 x bf16 MFMA frag

struct alignas(128) PadInt { int v; int pad[31]; };
__device__ PadInt g_cnt[NG];   // per-group cumulative arrival counters
__device__ PadInt g_flag[NG];  // per-group completed-step counters

// ---- MALL-coherent access helpers (bypass L1+L2) ---------------------------
__device__ __forceinline__ f4 ld_sys_x4(const float* p) {
  f4 v;
  asm volatile("global_load_dwordx4 %0, %1, off sc0 sc1" : "=v"(v) : "v"(p));
  return v;  // NOT ready until wait_vm0()
}
__device__ __forceinline__ int ld_sys_i32(const int* p) {
  int v;
  asm volatile("global_load_dword %0, %1, off sc0 sc1\n\ts_waitcnt vmcnt(0)"
               : "=v"(v) : "v"(p) : "memory");
  return v;
}
__device__ __forceinline__ void st_sys_f32(float* p, float v) {
  asm volatile("global_store_dword %0, %1, off sc0 sc1 nt" ::"v"(p), "v"(v)
               : "memory");
}
__device__ __forceinline__ void wait_vm0(void) {
  asm volatile("s_waitcnt vmcnt(0)" ::: "memory");
  __builtin_amdgcn_sched_barrier(0);
}

__device__ __forceinline__ void arrive_cnt(int g, int t) {
  int old = __hip_atomic_fetch_add(&g_cnt[g].v, 1, __ATOMIC_RELAXED,
                                   __HIP_MEMORY_SCOPE_AGENT);
  if (old == t * GM + (GM - 1))  // last arriver of this step: publish
    __hip_atomic_store(&g_flag[g].v, t + 1, __ATOMIC_RELAXED,
                       __HIP_MEMORY_SCOPE_AGENT);
}
__device__ __forceinline__ void pollf(int g, int e) {
  while (ld_sys_i32(&g_flag[g].v) < e) __builtin_amdgcn_s_sleep(1);
}

// ---- fp32 <-> bf16 (RNE) helpers -------------------------------------------
__device__ __forceinline__ unsigned short f2bf(float f) {
  unsigned u = __builtin_bit_cast(unsigned, f);
  u = u + 0x7FFFu + ((u >> 16) & 1u);
  return (unsigned short)(u >> 16);
}
__device__ __forceinline__ float bf2f(unsigned short b) {
  unsigned u = ((unsigned)b) << 16;
  return __builtin_bit_cast(float, u);
}
// 8 consecutive floats -> hi + lo bf16 frags
__device__ __forceinline__ void mk8hilo(const float* p, bs8& hi, bs8& lo) {
  f4 a = *reinterpret_cast<const f4*>(p);
  f4 b = *reinterpret_cast<const f4*>(p + 4);
  float v[8] = {a[0], a[1], a[2], a[3], b[0], b[1], b[2], b[3]};
#pragma unroll
  for (int j = 0; j < 8; ++j) {
    unsigned short h = f2bf(v[j]);
    hi[j] = (short)h;
    lo[j] = (short)f2bf(v[j] - bf2f(h));
  }
}

// ---------------------------------------------------------------------------
// W_self = 0.5*(W + W^T); also re-initializes the barrier state.
// ---------------------------------------------------------------------------
__global__ __launch_bounds__(256) void symm_k(const float* __restrict__ W,
                                              float* __restrict__ Ws) {
  if (blockIdx.x == 0 && blockIdx.y == 0 && threadIdx.x < NG) {
    __hip_atomic_store(&g_cnt[threadIdx.x].v, 0, __ATOMIC_RELAXED,
                       __HIP_MEMORY_SCOPE_AGENT);
    __hip_atomic_store(&g_flag[threadIdx.x].v, 0, __ATOMIC_RELAXED,
                       __HIP_MEMORY_SCOPE_AGENT);
  }
  int j = blockIdx.x * 16 + (threadIdx.x & 15);
  int i = blockIdx.y * 16 + (threadIdx.x >> 4);
  Ws[(size_t)i * N + j] = 0.5f * (W[(size_t)i * N + j] + W[(size_t)j * N + i]);
}

// ---------------------------------------------------------------------------
// x_proj = A (M x K) . B^T, B = W_input (N x K) row-major. 128x128 tile.
// XCD-aware swizzle: each XCD owns a contiguous bm chunk x all 8 bn.
// ---------------------------------------------------------------------------
__global__ __launch_bounds__(256) void xproj_gemm(const float* __restrict__ A,
                                                  const float* __restrict__ B,
                                                  float* __restrict__ C,
                                                  int M) {
  constexpr int BM = 128, BN = 128, BK = 16;
  __shared__ float As[BK][BM + 4];
  __shared__ float Bs[BK][BN + 4];

  const int tid = threadIdx.x;
  const int lin = blockIdx.x + gridDim.x * blockIdx.y;  // 0..2047
  const int sw  = ((lin & 7) << 8) + (lin >> 3);        // bijective (2048%8==0)
  const int bm  = sw >> 3;                              // 0..255
  const int bn  = sw & 7;                               // 0..7
  const int tx = tid & 15, ty = tid >> 4;
  const int K = N;

  float acc[8][8];
#pragma unroll
  for (int i = 0; i < 8; ++i)
#pragma unroll
    for (int j = 0; j < 8; ++j) acc[i][j] = 0.f;

  for (int kt = 0; kt < K; kt += BK) {
#pragma unroll
    for (int s = 0; s < 2; ++s) {
      int f = tid + s * 256;
      int row = f >> 2, kq = f & 3;
      float4 a = *reinterpret_cast<const float4*>(
          &A[(size_t)(bm * BM + row) * K + kt + kq * 4]);
      As[kq * 4 + 0][row] = a.x;
      As[kq * 4 + 1][row] = a.y;
      As[kq * 4 + 2][row] = a.z;
      As[kq * 4 + 3][row] = a.w;
      float4 b = *reinterpret_cast<const float4*>(
          &B[(size_t)(bn * BN + row) * K + kt + kq * 4]);
      Bs[kq * 4 + 0][row] = b.x;
      Bs[kq * 4 + 1][row] = b.y;
      Bs[kq * 4 + 2][row] = b.z;
      Bs[kq * 4 + 3][row] = b.w;
    }
    __syncthreads();

#pragma unroll
    for (int k = 0; k < BK; ++k) {
      float a[8], b[8];
      *reinterpret_cast<float4*>(&a[0]) =
          *reinterpret_cast<const float4*>(&As[k][ty * 8]);
      *reinterpret_cast<float4*>(&a[4]) =
          *reinterpret_cast<const float4*>(&As[k][ty * 8 + 4]);
      *reinterpret_cast<float4*>(&b[0]) =
          *reinterpret_cast<const float4*>(&Bs[k][tx * 8]);
      *reinterpret_cast<float4*>(&b[4]) =
          *reinterpret_cast<const float4*>(&Bs[k][tx * 8 + 4]);
#pragma unroll
      for (int i = 0; i < 8; ++i)
#pragma unroll
        for (int j = 0; j < 8; ++j) acc[i][j] = fmaf(a[i], b[j], acc[i][j]);
    }
    __syncthreads();
  }

#pragma unroll
  for (int i = 0; i < 8; ++i) {
    size_t row = (size_t)bm * BM + ty * 8 + i;
#pragma unroll
    for (int j = 0; j < 8; j += 4) {
      *reinterpret_cast<float4*>(&C[row * N + bn * BN + tx * 8 + j]) =
          *reinterpret_cast<const float4*>(&acc[i][j]);
    }
  }
}

// ---------------------------------------------------------------------------
// Persistent recurrence: R22 (3-pass split MFMA, zero compute converts)
// + DISTRIBUTED epilogue: each compute wave reduces/stores its own 16
// outputs (8 parallel store-ack RTs instead of wave-0-serial ~1 us/chain).
// 256 WGs x 640 thr, 1 WG/CU (LDS ~157 KiB).  WG (p=wg&15, cg=wg>>4):
// cols m0=cg*64, groups gA=2p, gB=2p+1 (2 batches each).
// Compute wave w: MFMA partial (K=128) -> red; ws-spin (all 8 partials);
// reduce cols [8w,8w+8) x 2 batches (16 lanes, conflict-free stride-128
// reads); tanh+xp; st_sys; wait_vm0; ack.  Sync waves 8/9: R17 handshake
// (ack target 8t) + stage h + split hi/lo bf16 + xp prefetch-ahead.
// Data path sc0+sc1 / nt write-through (MALL-coherent), R7+ lineage.
// ---------------------------------------------------------------------------
__global__ __launch_bounds__(640, 1) void rnn_persist(
    float* __restrict__ out, const float* __restrict__ Ws) {
  const int tid = threadIdx.x;
  const int wg  = blockIdx.x;
  const int p   = wg & 15;
  const int cg  = wg >> 4;
  const int m0  = cg * 64;
  const int gA  = 2 * p, gB = 2 * p + 1;
  const int b0A = gA * 2, b0B = gB * 2;
  const size_t TN = (size_t)T * N;

  __shared__ __align__(16) short wloF[65536];      // 131,072 B (frag-ordered)
  __shared__ __align__(16) short hsA[4][1032];     // 8,256 B (hi,hi,lo,lo)
  __shared__ __align__(16) short hsB[4][1032];     // 8,256 B
  __shared__ float xplA[128], xplB[128];           // 1,024 B
  __shared__ float redA[8 * 128], redB[8 * 128];   // 8,192 B
  __shared__ int lflags[64];
  // [0]=readyA [16]=readyB [8]=wsA [24]=wsB [32]=ackA [48]=ackB

  if (tid == 0) {
    lflags[0] = -1; lflags[16] = -1;
    lflags[8] = 0;  lflags[24] = 0;
    lflags[32] = 0; lflags[48] = 0;
  }

  const int l = tid & 63;
  const int v = tid >> 6;           // 0-7 compute, 8=syncA, 9=syncB
  const int n = l & 15;
  const int g = l >> 4;

  // ---- prologue: Whi -> VGPR frags; Wlo -> fragment-ordered LDS ----
  bs8 whi[4][4];  // [mt][kt]: W[m0+16mt+n][128v+32kt+8g .. +7]
  if (v < 8) {
#pragma unroll
    for (int mt = 0; mt < 4; ++mt)
#pragma unroll
      for (int kt = 0; kt < 4; ++kt) {
        bs8 hi, lo;
        mk8hilo(&Ws[(size_t)(m0 + 16 * mt + n) * N + 128 * v + 32 * kt + 8 * g],
                hi, lo);
        whi[mt][kt] = hi;
        *reinterpret_cast<bs8*>(
            &wloF[((((v * 4 + mt) * 4 + kt) * 4 + g) * 16 + n) * 8]) = lo;
      }
  }
  __syncthreads();

  if (v < 8) {
    // ================= COMPUTE WAVES (MFMA + distributed epilogue) ========
    const int koff = 128 * v + 8 * g;   // this lane's k base (shorts)
    const int hrow = n & 1;             // batch row for B-fragment
    const int rcol = 8 * v + (l & 7);   // reduce: own column
    const int rnb  = (l >> 3) & 1;      // reduce: own batch (lanes 0..15)

    auto do_chain = [&](short (*hsX)[1032], float* xplX, float* redX,
                        int rdyIdx, int wsIdx, int ackIdx, int b0, int t) {
      while (*(volatile int*)&lflags[rdyIdx] < t) __builtin_amdgcn_s_sleep(1);
      __builtin_amdgcn_fence(__ATOMIC_ACQUIRE, "workgroup");
      if (t > 0) {
        f4 acc0 = {0.f, 0.f, 0.f, 0.f}, acc1 = {0.f, 0.f, 0.f, 0.f};
        f4 acc2 = {0.f, 0.f, 0.f, 0.f}, acc3 = {0.f, 0.f, 0.f, 0.f};
#pragma unroll
        for (int kt = 0; kt < 4; ++kt) {
          bs8 bhi = *reinterpret_cast<const bs8*>(&hsX[hrow][koff + 32 * kt]);
          bs8 blo = *reinterpret_cast<const bs8*>(&hsX[2 + hrow][koff + 32 * kt]);
          bs8 wl0 = *reinterpret_cast<const bs8*>(
              &wloF[((((v * 4 + 0) * 4 + kt) * 4 + g) * 16 + n) * 8]);
          bs8 wl1 = *reinterpret_cast<const bs8*>(
              &wloF[((((v * 4 + 1) * 4 + kt) * 4 + g) * 16 + n) * 8]);
          bs8 wl2 = *reinterpret_cast<const bs8*>(
              &wloF[((((v * 4 + 2) * 4 + kt) * 4 + g) * 16 + n) * 8]);
          bs8 wl3 = *reinterpret_cast<const bs8*>(
              &wloF[((((v * 4 + 3) * 4 + kt) * 4 + g) * 16 + n) * 8]);
          acc0 = __builtin_amdgcn_mfma_f32_16x16x32_bf16(whi[0][kt], bhi, acc0, 0, 0, 0);
          acc0 = __builtin_amdgcn_mfma_f32_16x16x32_bf16(whi[0][kt], blo, acc0, 0, 0, 0);
          acc0 = __builtin_amdgcn_mfma_f32_16x16x32_bf16(wl0, bhi, acc0, 0, 0, 0);
          acc1 = __builtin_amdgcn_mfma_f32_16x16x32_bf16(whi[1][kt], bhi, acc1, 0, 0, 0);
          acc1 = __builtin_amdgcn_mfma_f32_16x16x32_bf16(whi[1][kt], blo, acc1, 0, 0, 0);
          acc1 = __builtin_amdgcn_mfma_f32_16x16x32_bf16(wl1, bhi, acc1, 0, 0, 0);
          acc2 = __builtin_amdgcn_mfma_f32_16x16x32_bf16(whi[2][kt], bhi, acc2, 0, 0, 0);
          acc2 = __builtin_amdgcn_mfma_f32_16x16x32_bf16(whi[2][kt], blo, acc2, 0, 0, 0);
          acc2 = __builtin_amdgcn_mfma_f32_16x16x32_bf16(wl2, bhi, acc2, 0, 0, 0);
          acc3 = __builtin_amdgcn_mfma_f32_16x16x32_bf16(whi[3][kt], bhi, acc3, 0, 0, 0);
          acc3 = __builtin_amdgcn_mfma_f32_16x16x32_bf16(whi[3][kt], blo, acc3, 0, 0, 0);
          acc3 = __builtin_amdgcn_mfma_f32_16x16x32_bf16(wl3, bhi, acc3, 0, 0, 0);
        }
        if (n < 2) {  // D: col=n (batch), row=4g+r (m within 16-tile)
          const int rb = 4 * g;
#pragma unroll
          for (int r = 0; r < 4; ++r) {
            redX[v * 128 + (0  + rb + r) * 2 + n] = acc0[r];
            redX[v * 128 + (16 + rb + r) * 2 + n] = acc1[r];
            redX[v * 128 + (32 + rb + r) * 2 + n] = acc2[r];
            redX[v * 128 + (48 + rb + r) * 2 + n] = acc3[r];
          }
        }
      }
      __builtin_amdgcn_fence(__ATOMIC_RELEASE, "workgroup");
      if (l == 0) atomicAdd(&lflags[wsIdx], 1);
      // all compute waves: wait for all 8 partials of this step
      while (*(volatile int*)&lflags[wsIdx] < 8 * (t + 1))
        __builtin_amdgcn_s_sleep(1);
      __builtin_amdgcn_fence(__ATOMIC_ACQUIRE, "workgroup");
      // distributed reduce/store: wave v owns cols [8v, 8v+8) x 2 batches
      if (l < 16) {
        float pre = 0.f;
        if (t > 0) {
#pragma unroll
          for (int w = 0; w < 8; ++w)
            pre += redX[w * 128 + rcol * 2 + rnb];
        }
        float h = tanhf(pre + xplX[rnb * 64 + rcol]);
        st_sys_f32(out + (size_t)(b0 + rnb) * TN + (size_t)t * N + m0 + rcol,
                   h);
      }
      wait_vm0();  // own stores acked at MALL (8 waves in parallel)
      if (l == 0) atomicAdd(&lflags[ackIdx], 1);
    };

    for (int t = 0; t < T; ++t) {
      do_chain(hsA, xplA, redA, 0, 8, 32, b0A, t);
      do_chain(hsB, xplB, redB, 16, 24, 48, b0B, t);
    }
  } else {
    // ================= SYNC/STAGE WAVES =================
    const bool isB = (v == 9);
    const int lane = l;
    const int grp  = isB ? gB : gA;
    const int b0   = isB ? b0B : b0A;
    short (*hsb)[1032] = isB ? hsB : hsA;
    float* xpl = isB ? xplB : xplA;
    volatile int* ready = isB ? (volatile int*)&lflags[16]
                              : (volatile int*)&lflags[0];
    volatile int* cnt = isB ? (volatile int*)&lflags[48]
                            : (volatile int*)&lflags[32];

    const int r = lane >> 5;   // h row 0..1 (32 lanes per row)
    const int c = lane & 31;
    const float* hrow = out + (size_t)(b0 + r) * TN;
    const int xr = lane >> 4, xc = (lane & 15) * 4;  // lane<32: 2 rows x 64 col
    const float* xsrc = out + (size_t)(b0 + xr) * TN + m0 + xc;

    // stage xp(0); publish ready=0; prefetch xp(1) (own cols -> safe early)
    f4 xnext;
    {
      f4 xv;
      if (lane < 32) xv = ld_sys_x4(xsrc);
      wait_vm0();
      if (lane < 32) *reinterpret_cast<f4*>(&xpl[xr * 64 + xc]) = xv;
      __builtin_amdgcn_fence(__ATOMIC_RELEASE, "workgroup");
      if (lane == 0) *ready = 0;
      if (lane < 32) xnext = ld_sys_x4(xsrc + (size_t)N);
    }

    for (int t = 1; t < T; ++t) {
      if (lane == 0) {
        while (*cnt < 8 * t) __builtin_amdgcn_s_sleep(1);  // 8 acks of t-1
        arrive_cnt(grp, t - 1);                            // global arrive
        pollf(grp, t);                                     // wait group done
      }
      // stage h(t-1) (8 KB) and SPLIT to hi/lo bf16 rows
      const float* hs = hrow + (size_t)(t - 1) * N;
      f4 tmp[8];
#pragma unroll
      for (int q = 0; q < 8; ++q) tmp[q] = ld_sys_x4(hs + 4 * (c + 32 * q));
      wait_vm0();
#pragma unroll
      for (int q = 0; q < 8; ++q) {
        s4 hi4, lo4;
#pragma unroll
        for (int j = 0; j < 4; ++j) {
          float x = tmp[q][j];
          unsigned short h = f2bf(x);
          hi4[j] = (short)h;
          lo4[j] = (short)f2bf(x - bf2f(h));
        }
        *reinterpret_cast<s4*>(&hsb[r][4 * (c + 32 * q)]) = hi4;
        *reinterpret_cast<s4*>(&hsb[2 + r][4 * (c + 32 * q)]) = lo4;
      }
      if (lane < 32) *reinterpret_cast<f4*>(&xpl[xr * 64 + xc]) = xnext;
      __builtin_amdgcn_fence(__ATOMIC_RELEASE, "workgroup");
      if (lane == 0) *ready = t;
      if (t + 1 < T && lane < 32)
        xnext = ld_sys_x4(xsrc + (size_t)(t + 1) * N);
    }
  }
}

// ---------------------------------------------------------------------------
extern "C" void kernel_launch(void* const* d_in, const int* in_sizes, int n_in,
                              void* d_out, int out_size, void* d_ws,
                              size_t ws_size, hipStream_t stream) {
  const float* in_seq  = (const float*)d_in[0];  // (64,512,1024)
  const float* W_lower = (const float*)d_in[1];  // (1024,1024)
  const float* W_input = (const float*)d_in[2];  // (1024,1024)
  float* out = (float*)d_out;                    // (64,512,1024)
  float* Ws  = (float*)d_ws;                     // 4 MiB scratch

  symm_k<<<dim3(N / 16, N / 16), 256, 0, stream>>>(W_lower, Ws);
  xproj_gemm<<<dim3(N / 128, (BATCH * T) / 128), 256, 0, stream>>>(
      in_seq, W_input, out, BATCH * T);
  rnn_persist<<<NWG, 640, 0, stream>>>(out, Ws);
}